// Round 8
// baseline (239.924 us; speedup 1.0000x reference)
//
#include <hip/hip_runtime.h>
#include <hip/hip_bf16.h>
#include <hip/hip_fp8.h>

#define SEQ 4096
#define DIM 1024

using f32x4  = __attribute__((ext_vector_type(4))) float;
using bf16x8 = __attribute__((ext_vector_type(8))) short;

static __device__ __forceinline__ float bf2f(unsigned short u) {
  unsigned int x = ((unsigned int)u) << 16;
  return __builtin_bit_cast(float, x);
}
static __device__ __forceinline__ unsigned short f2bf(float f) {
  unsigned int x = __builtin_bit_cast(unsigned int, f);
  unsigned int r = (x + 0x7fff + ((x >> 16) & 1)) >> 16;  // RNE
  return (unsigned short)r;
}
static __device__ __forceinline__ unsigned char f2fp8(float f) {
  __hip_fp8_e4m3 h(f);  // OCP e4m3fn
  return h.__x;
}

// ---- x -> bf16; out[:, :1024] = x (fp32); out[:, 1024:2048] = 0 ----
__global__ __launch_bounds__(256) void convert_x_kernel(
    const float* __restrict__ x, unsigned short* __restrict__ xb,
    float* __restrict__ out) {
  int idx = blockIdx.x * 256 + threadIdx.x;  // one thread per 4 floats
  int e = idx * 4;
  int i = e >> 10;
  int d = e & 1023;
  float4 v = *(const float4*)(x + (size_t)e);
  *(float4*)(out + (size_t)i * 2048 + d) = v;
  *(float4*)(out + (size_t)i * 2048 + 1024 + d) = make_float4(0.f, 0.f, 0.f, 0.f);
  ushort4 p;
  p.x = f2bf(v.x); p.y = f2bf(v.y); p.z = f2bf(v.z); p.w = f2bf(v.w);
  *(ushort4*)(xb + (size_t)e) = p;
}

// ---- prep: 3x W transpose ([in][out] f32 -> [out][in] bf16) + bias concat ----
__global__ __launch_bounds__(256) void prep_kernel(
    const float* __restrict__ Wq, const float* __restrict__ Wk,
    const float* __restrict__ Wv, const float* __restrict__ bq,
    const float* __restrict__ bk, const float* __restrict__ bv,
    unsigned short* __restrict__ Wcat, float* __restrict__ bcat) {
  int b = blockIdx.x;
  if (b < 3072) {
    int m  = b >> 10;
    int tt = b & 1023;
    const float* in = (m == 0) ? Wq : (m == 1) ? Wk : Wv;
    unsigned short* out = Wcat + (size_t)m * DIM * DIM;
    __shared__ float tile[32][33];
    int bx = (tt & 31) * 32, by = (tt >> 5) * 32;
    int tx = threadIdx.x & 31, ty = threadIdx.x >> 5;
#pragma unroll
    for (int r = 0; r < 32; r += 8)
      tile[ty + r][tx] = in[(size_t)(by + ty + r) * DIM + bx + tx];
    __syncthreads();
#pragma unroll
    for (int r = 0; r < 32; r += 8)
      out[(size_t)(bx + ty + r) * DIM + by + tx] = f2bf(tile[tx][ty + r]);
  } else {
    int i = (b - 3072) * 256 + threadIdx.x;  // 12 blocks -> 3072 elems
    float v = (i < 1024) ? bq[i] : (i < 2048 ? bk[i - 1024] : bv[i - 2048]);
    bcat[i] = v;
  }
}

// ---- transpose V (bf16 [4096][1024]) -> Vt (bf16 [1024][4096]) + zero lrow ----
__global__ __launch_bounds__(256) void transpose_v_kernel(
    const unsigned short* __restrict__ in, int ld_in,
    unsigned short* __restrict__ out, int ld_out,
    float* __restrict__ lrow) {
  if (blockIdx.y == 0 && blockIdx.x < 16)
    lrow[blockIdx.x * 256 + threadIdx.x] = 0.0f;
  __shared__ unsigned short tile[32][33];
  int bx = blockIdx.x * 32;  // c base (V col)
  int by = blockIdx.y * 32;  // r base (V row)
  int tx = threadIdx.x & 31;
  int ty = threadIdx.x >> 5;
#pragma unroll
  for (int r = 0; r < 32; r += 8)
    tile[ty + r][tx] = in[(size_t)(by + ty + r) * ld_in + bx + tx];
  __syncthreads();
#pragma unroll
  for (int r = 0; r < 32; r += 8)
    out[(size_t)(bx + ty + r) * ld_out + by + tx] = tile[tx][ty + r];
}

// ---- QKV GEMM (bf16, BK=64, 8-slot XOR swizzle) + LDS-staged epilogue ----
// C = Xb @ Wcat^T + bcat. Per-block output type is uniform (j0 block of 128
// inside 0..1023=Q, 1024..2047=K, 2048..3071=V). Q -> fp8 (x1/32), K -> fp8,
// V -> bf16, all via LDS re-layout then full-line coalesced stores.
__global__ __launch_bounds__(256) void gemm_qkv(
    const unsigned short* __restrict__ A, const unsigned short* __restrict__ B,
    const float* __restrict__ bias,
    unsigned char* __restrict__ Qf8, unsigned char* __restrict__ Kf8,
    unsigned short* __restrict__ Vb) {
  const int tid  = threadIdx.x;
  const int wave = tid >> 6;
  const int lane = tid & 63;
  const int wm = wave >> 1, wn = wave & 1;

  int lin = blockIdx.x + 24 * blockIdx.y;
  int xcd = lin & 7, idx = lin >> 3;  // idx in [0,96)
  const int i0 = (xcd * 4 + idx / 24) * 128;
  const int j0 = (idx % 24) * 128;
  const int lda = DIM, ldb = DIM;

  __shared__ unsigned char smem[32768];
  unsigned short* lA = (unsigned short*)smem;              // 16 KB
  unsigned short* lB = (unsigned short*)(smem + 16384);    // 16 KB

  f32x4 acc[4][4];
#pragma unroll
  for (int a = 0; a < 4; ++a)
#pragma unroll
    for (int b = 0; b < 4; ++b) acc[a][b] = (f32x4){0.f, 0.f, 0.f, 0.f};

  const int l15  = lane & 15;
  const int quad = lane >> 4;
  const int r7   = l15 & 7;
  const int cbase = wave * 256;

  for (int kt = 0; kt < DIM; kt += 64) {
    const unsigned short* gA = A + (size_t)i0 * lda + kt;
    const unsigned short* gB = B + (size_t)j0 * ldb + kt;
#pragma unroll
    for (int t = 0; t < 4; ++t) {
      int c  = cbase + t * 64 + lane;
      int r  = c >> 3;
      int sl = c & 7;
      int g  = sl ^ (r & 7);
      __builtin_amdgcn_global_load_lds(
          (const __attribute__((address_space(1))) void*)(gA + (size_t)r * lda + g * 8),
          (__attribute__((address_space(3))) void*)(&lA[c * 8]), 16, 0, 0);
      __builtin_amdgcn_global_load_lds(
          (const __attribute__((address_space(1))) void*)(gB + (size_t)r * ldb + g * 8),
          (__attribute__((address_space(3))) void*)(&lB[c * 8]), 16, 0, 0);
    }
    __syncthreads();
#pragma unroll
    for (int kf = 0; kf < 2; ++kf) {
      bf16x8 af[4], bfr[4];
#pragma unroll
      for (int mt = 0; mt < 4; ++mt)
        af[mt] = *(const bf16x8*)&lA[(wm * 64 + mt * 16 + l15) * 64 + ((kf * 4 + quad) ^ r7) * 8];
#pragma unroll
      for (int nt = 0; nt < 4; ++nt)
        bfr[nt] = *(const bf16x8*)&lB[(wn * 64 + nt * 16 + l15) * 64 + ((kf * 4 + quad) ^ r7) * 8];
#pragma unroll
      for (int mt = 0; mt < 4; ++mt)
#pragma unroll
        for (int nt = 0; nt < 4; ++nt)
          acc[mt][nt] = __builtin_amdgcn_mfma_f32_16x16x32_bf16(af[mt], bfr[nt], acc[mt][nt], 0, 0, 0);
    }
    __syncthreads();
  }

  // ---- LDS-staged epilogue (C/D layout: col=lane&15, row=quad*4+reg) ----
  const int type = j0 >> 10;        // 0=Q, 1=K, 2=V
  const int jl   = j0 & 1023;
  const float scale = (type == 0) ? 0.03125f : 1.0f;

  if (type < 2) {
    // fp8 tile [128 rows][128 B], chunk(16B) c of row r stored at slot c^(r&7)
    unsigned char* ep = smem;
#pragma unroll
    for (int nt = 0; nt < 4; ++nt) {
      int cl = wn * 64 + nt * 16 + l15;
      float bv = bias[j0 + cl];
      int ch = wn * 4 + nt;
#pragma unroll
      for (int mt = 0; mt < 4; ++mt) {
        int rl0 = wm * 64 + mt * 16 + quad * 4;
#pragma unroll
        for (int r = 0; r < 4; ++r) {
          int rl = rl0 + r;
          ep[rl * 128 + (ch ^ (rl & 7)) * 16 + l15] = f2fp8((acc[mt][nt][r] + bv) * scale);
        }
      }
    }
    __syncthreads();
    int row = tid >> 1, half = tid & 1;
    unsigned char* dst = (type == 0 ? Qf8 : Kf8) + (size_t)(i0 + row) * 1024 + jl + half * 64;
#pragma unroll
    for (int k = 0; k < 4; ++k) {
      int sl = (half * 4 + k) ^ (row & 7);
      *(float4*)(dst + k * 16) = *(const float4*)(ep + row * 128 + sl * 16);
    }
  } else {
    // bf16 tile [128 rows][256 B] (16 chunks of 16B), slot = c ^ (r&7)
    unsigned short* ep = (unsigned short*)smem;
#pragma unroll
    for (int nt = 0; nt < 4; ++nt) {
      int cl = wn * 64 + nt * 16 + l15;
      float bv = bias[j0 + cl];
      int chv = cl >> 3, within = cl & 7;
#pragma unroll
      for (int mt = 0; mt < 4; ++mt) {
        int rl0 = wm * 64 + mt * 16 + quad * 4;
#pragma unroll
        for (int r = 0; r < 4; ++r) {
          int rl = rl0 + r;
          ep[rl * 128 + (chv ^ (rl & 7)) * 8 + within] = f2bf(acc[mt][nt][r] + bv);
        }
      }
    }
    __syncthreads();
    int row = tid >> 1, half = tid & 1;
    unsigned short* dst = Vb + (size_t)(i0 + row) * 1024 + jl + half * 64;
#pragma unroll
    for (int k = 0; k < 8; ++k) {
      int sl = (half * 8 + k) ^ (row & 7);
      *(float4*)(dst + k * 8) = *(const float4*)(ep + row * 128 + sl * 8);
    }
  }
}

// ---- scores: fp8 BT GEMM, BK=128, 528 upper-tri tiles (66/XCD) ----
// Epilogue: P = exp(S-4) -> bf16 Pr via LDS re-layout (coalesced stores),
// row-sums of the stored bf16 values atomically into lrow.
__global__ __launch_bounds__(256) void gemm_sc(
    const unsigned char* __restrict__ A, const unsigned char* __restrict__ B,
    unsigned short* __restrict__ Pr, float* __restrict__ lrow) {
  const int tid  = threadIdx.x;
  const int wave = tid >> 6;
  const int lane = tid & 63;
  const int wm = wave >> 1, wn = wave & 1;

  int b = blockIdx.x;
  int t = (b & 7) * 66 + (b >> 3);
  int bi = (int)floorf((65.0f - sqrtf(4225.0f - 8.0f * (float)t)) * 0.5f);
  while (bi > 0 && (bi * (65 - bi)) / 2 > t) --bi;
  while (((bi + 1) * (64 - bi)) / 2 <= t) ++bi;
  int bj = bi + (t - (bi * (65 - bi)) / 2);
  const int i0 = bi * 128, j0 = bj * 128;
  const int lda = DIM, ldb = DIM;

  __shared__ unsigned char smem[32768];
  unsigned char* lA = smem;            // 16 KB [128][128B]
  unsigned char* lB = smem + 16384;    // 16 KB

  f32x4 acc[4][4];
#pragma unroll
  for (int a = 0; a < 4; ++a)
#pragma unroll
    for (int bb = 0; bb < 4; ++bb) acc[a][bb] = (f32x4){0.f, 0.f, 0.f, 0.f};

  const int l15  = lane & 15;
  const int quad = lane >> 4;
  const int r7   = l15 & 7;
  const int cbase = wave * 256;

  for (int kt = 0; kt < DIM; kt += 128) {
    const unsigned char* gA = A + (size_t)i0 * lda + kt;
    const unsigned char* gB = B + (size_t)j0 * ldb + kt;
#pragma unroll
    for (int tt = 0; tt < 4; ++tt) {
      int c  = cbase + tt * 64 + lane;
      int r  = c >> 3;
      int sl = c & 7;
      int g  = sl ^ (r & 7);
      __builtin_amdgcn_global_load_lds(
          (const __attribute__((address_space(1))) void*)(gA + (size_t)r * lda + g * 16),
          (__attribute__((address_space(3))) void*)(&lA[c * 16]), 16, 0, 0);
      __builtin_amdgcn_global_load_lds(
          (const __attribute__((address_space(1))) void*)(gB + (size_t)r * ldb + g * 16),
          (__attribute__((address_space(3))) void*)(&lB[c * 16]), 16, 0, 0);
    }
    __syncthreads();
#pragma unroll
    for (int kf = 0; kf < 4; ++kf) {
      long av[4], bvv[4];
#pragma unroll
      for (int mt = 0; mt < 4; ++mt) {
        int row = wm * 64 + mt * 16 + l15;
        int ch  = (kf * 2 + (quad >> 1)) ^ r7;
        av[mt] = *(const long*)&lA[row * 128 + ch * 16 + (quad & 1) * 8];
      }
#pragma unroll
      for (int nt = 0; nt < 4; ++nt) {
        int row = wn * 64 + nt * 16 + l15;
        int ch  = (kf * 2 + (quad >> 1)) ^ r7;
        bvv[nt] = *(const long*)&lB[row * 128 + ch * 16 + (quad & 1) * 8];
      }
#pragma unroll
      for (int mt = 0; mt < 4; ++mt)
#pragma unroll
        for (int nt = 0; nt < 4; ++nt)
          acc[mt][nt] = __builtin_amdgcn_mfma_f32_16x16x32_fp8_fp8(av[mt], bvv[nt], acc[mt][nt], 0, 0, 0);
    }
    __syncthreads();
  }

  // ---- epilogue: bf16 P tile [128][128] shorts via LDS, + lrow sums ----
  unsigned short* ep = (unsigned short*)smem;
  float lsum[4][4];
#pragma unroll
  for (int mt = 0; mt < 4; ++mt)
#pragma unroll
    for (int r = 0; r < 4; ++r) lsum[mt][r] = 0.0f;
#pragma unroll
  for (int nt = 0; nt < 4; ++nt) {
    int cl = wn * 64 + nt * 16 + l15;
    int gc = j0 + cl;
    int chv = cl >> 3, within = cl & 7;
#pragma unroll
    for (int mt = 0; mt < 4; ++mt) {
      int rl0 = wm * 64 + mt * 16 + quad * 4;
#pragma unroll
      for (int r = 0; r < 4; ++r) {
        int rl = rl0 + r;
        int row = i0 + rl;
        float e = (gc >= row) ? __expf(acc[mt][nt][r] - 4.0f) : 0.0f;
        unsigned short eb = f2bf(e);
        ep[rl * 128 + (chv ^ (rl & 7)) * 8 + within] = eb;
        lsum[mt][r] += bf2f(eb);  // sum what PV will actually read
      }
    }
  }
#pragma unroll
  for (int mt = 0; mt < 4; ++mt)
#pragma unroll
    for (int r = 0; r < 4; ++r) {
      float s = lsum[mt][r];
      s += __shfl_xor(s, 1);
      s += __shfl_xor(s, 2);
      s += __shfl_xor(s, 4);
      s += __shfl_xor(s, 8);
      if (l15 == 0)
        unsafeAtomicAdd(&lrow[i0 + wm * 64 + mt * 16 + quad * 4 + r], s);
    }
  __syncthreads();
  int row = tid >> 1, half = tid & 1;
  unsigned short* dst = Pr + (size_t)(i0 + row) * SEQ + j0 + half * 64;
#pragma unroll
  for (int k = 0; k < 8; ++k) {
    int sl = (half * 8 + k) ^ (row & 7);
    *(float4*)(dst + k * 8) = *(const float4*)(ep + row * 128 + sl * 8);
  }
}

// ---- PV: bf16 BT GEMM, BK=64, split-K z=4x1024, identity grid ----
// Epilogue scales by 1/lrow, fp32 atomicAdd into out[:,1024:2048].
__global__ __launch_bounds__(256) void gemm_pv(
    const unsigned short* __restrict__ A, int lda,
    const unsigned short* __restrict__ B, int ldb,
    float* __restrict__ Cf, const float* __restrict__ lrow,
    int ldc, int ccol) {
  const int tid  = threadIdx.x;
  const int wave = tid >> 6;
  const int lane = tid & 63;
  const int wm = wave >> 1, wn = wave & 1;

  const int i0 = blockIdx.y * 128, j0 = blockIdx.x * 128;
  int kc0 = blockIdx.z * 1024;
  int kend = kc0 + 1024;
  if (kend <= i0) return;               // chunk entirely in zero region
  int kstart = (kc0 > i0) ? kc0 : i0;   // Pr cols < i0 are exactly zero

  __shared__ unsigned short lA[128 * 64];  // 16 KB
  __shared__ unsigned short lB[128 * 64];  // 16 KB

  f32x4 acc[4][4];
#pragma unroll
  for (int a = 0; a < 4; ++a)
#pragma unroll
    for (int b = 0; b < 4; ++b) acc[a][b] = (f32x4){0.f, 0.f, 0.f, 0.f};

  const int l15  = lane & 15;
  const int quad = lane >> 4;
  const int r7   = l15 & 7;
  const int cbase = wave * 256;

  for (int kt = kstart; kt < kend; kt += 64) {
    const unsigned short* gA = A + (size_t)i0 * lda + kt;
    const unsigned short* gB = B + (size_t)j0 * ldb + kt;
#pragma unroll
    for (int t = 0; t < 4; ++t) {
      int c  = cbase + t * 64 + lane;
      int r  = c >> 3;
      int sl = c & 7;
      int g  = sl ^ (r & 7);
      __builtin_amdgcn_global_load_lds(
          (const __attribute__((address_space(1))) void*)(gA + (size_t)r * lda + g * 8),
          (__attribute__((address_space(3))) void*)(&lA[c * 8]), 16, 0, 0);
      __builtin_amdgcn_global_load_lds(
          (const __attribute__((address_space(1))) void*)(gB + (size_t)r * ldb + g * 8),
          (__attribute__((address_space(3))) void*)(&lB[c * 8]), 16, 0, 0);
    }
    __syncthreads();
#pragma unroll
    for (int kf = 0; kf < 2; ++kf) {
      bf16x8 af[4], bfr[4];
#pragma unroll
      for (int mt = 0; mt < 4; ++mt)
        af[mt] = *(const bf16x8*)&lA[(wm * 64 + mt * 16 + l15) * 64 + ((kf * 4 + quad) ^ r7) * 8];
#pragma unroll
      for (int nt = 0; nt < 4; ++nt)
        bfr[nt] = *(const bf16x8*)&lB[(wn * 64 + nt * 16 + l15) * 64 + ((kf * 4 + quad) ^ r7) * 8];
#pragma unroll
      for (int mt = 0; mt < 4; ++mt)
#pragma unroll
        for (int nt = 0; nt < 4; ++nt)
          acc[mt][nt] = __builtin_amdgcn_mfma_f32_16x16x32_bf16(af[mt], bfr[nt], acc[mt][nt], 0, 0, 0);
    }
    __syncthreads();
  }

  float inv[4][4];
#pragma unroll
  for (int mt = 0; mt < 4; ++mt)
#pragma unroll
    for (int r = 0; r < 4; ++r)
      inv[mt][r] = 1.0f / lrow[i0 + wm * 64 + mt * 16 + quad * 4 + r];
#pragma unroll
  for (int nt = 0; nt < 4; ++nt) {
    int gc = j0 + wn * 64 + nt * 16 + l15;
#pragma unroll
    for (int mt = 0; mt < 4; ++mt) {
      int gr0 = i0 + wm * 64 + mt * 16 + quad * 4;
#pragma unroll
      for (int r = 0; r < 4; ++r)
        unsafeAtomicAdd(&Cf[(size_t)(gr0 + r) * ldc + ccol + gc],
                        acc[mt][nt][r] * inv[mt][r]);
    }
  }
}

extern "C" void kernel_launch(void* const* d_in, const int* in_sizes, int n_in,
                              void* d_out, int out_size, void* d_ws, size_t ws_size,
                              hipStream_t stream) {
  const float* x  = (const float*)d_in[0];
  const float* Wk = (const float*)d_in[1];
  const float* bk = (const float*)d_in[2];
  const float* Wq = (const float*)d_in[3];
  const float* bq = (const float*)d_in[4];
  const float* Wv = (const float*)d_in[5];
  const float* bv = (const float*)d_in[6];
  float* out = (float*)d_out;

  char* ws = (char*)d_ws;
  unsigned short* Xb   = (unsigned short*)(ws);                  // 8 MB  [4096][1024] bf16
  float*          lrow = (float*)(ws);                           // 16 KB, aliases Xb (dead after QKV)
  unsigned short* Wcat = (unsigned short*)(ws + (8ull << 20));   // 6 MB  [3072][1024] bf16
  float*          bcat = (float*)(ws + (14ull << 20));           // 12 KB
  unsigned char*  Qf8  = (unsigned char*)(ws + (15ull << 20));   // 4 MB  [4096][1024] fp8
  unsigned char*  Kf8  = (unsigned char*)(ws + (19ull << 20));   // 4 MB  [4096][1024] fp8
  unsigned short* Vb   = (unsigned short*)(ws + (23ull << 20));  // 8 MB  [4096][1024] bf16
  unsigned short* Vt   = (unsigned short*)(ws + (31ull << 20));  // 8 MB  [1024][4096] bf16
  unsigned short* Pr   = (unsigned short*)(ws + (39ull << 20));  // 32 MB [4096][4096] bf16

  // 1. x -> bf16 ; out[:, :1024] = x ; out[:, 1024:] = 0
  convert_x_kernel<<<SEQ * DIM / 4 / 256, 256, 0, stream>>>(x, Xb, out);

  // 2. W transposes + bias concat (one dispatch)
  prep_kernel<<<3084, 256, 0, stream>>>(Wq, Wk, Wv, bq, bk, bv, Wcat, bcat);

  // 3. fused QKV GEMM (bf16) -> Qf8 (x1/32), Kf8, Vb (coalesced LDS epilogue)
  gemm_qkv<<<dim3(24, 32), 256, 0, stream>>>(Xb, Wcat, bcat, Qf8, Kf8, Vb);

  // 4. Vt = V^T (bf16); also zeroes lrow (aliases dead Xb)
  transpose_v_kernel<<<dim3(DIM / 32, SEQ / 32), 256, 0, stream>>>(
      Vb, DIM, Vt, SEQ, lrow);

  // 5. scores upper-tri tiles (fp8 inputs) -> bf16 Pr + lrow sums
  gemm_sc<<<528, 256, 0, stream>>>(Qf8, Kf8, Pr, lrow);

  // 6. read = (P @ V) / l -> out[:, 1024:2048] (bf16 mfma, fp32 atomics)
  gemm_pv<<<dim3(8, 32, 4), 256, 0, stream>>>(
      Pr, SEQ, Vt, SEQ, out, lrow, 2048, 1024);
}

// Round 9
// 231.323 us; speedup vs baseline: 1.0372x; 1.0372x over previous
//
#include <hip/hip_runtime.h>
#include <hip/hip_bf16.h>
#include <hip/hip_fp8.h>

#define SEQ 4096
#define DIM 1024

using f32x4  = __attribute__((ext_vector_type(4))) float;
using bf16x8 = __attribute__((ext_vector_type(8))) short;

static __device__ __forceinline__ float bf2f(unsigned short u) {
  unsigned int x = ((unsigned int)u) << 16;
  return __builtin_bit_cast(float, x);
}
static __device__ __forceinline__ unsigned short f2bf(float f) {
  unsigned int x = __builtin_bit_cast(unsigned int, f);
  unsigned int r = (x + 0x7fff + ((x >> 16) & 1)) >> 16;  // RNE
  return (unsigned short)r;
}
static __device__ __forceinline__ unsigned char f2fp8(float f) {
  __hip_fp8_e4m3 h(f);  // OCP e4m3fn
  return h.__x;
}

// ---- fused: x -> bf16 + out[:, :1024] = x ; W transposes ; bias concat ----
__global__ __launch_bounds__(256) void setup_kernel(
    const float* __restrict__ x, unsigned short* __restrict__ xb,
    float* __restrict__ out,
    const float* __restrict__ Wq, const float* __restrict__ Wk,
    const float* __restrict__ Wv, const float* __restrict__ bq,
    const float* __restrict__ bk, const float* __restrict__ bv,
    unsigned short* __restrict__ Wcat, float* __restrict__ bcat) {
  int b = blockIdx.x;
  if (b < 4096) {
    int e = (b * 256 + threadIdx.x) * 4;
    int i = e >> 10;
    int d = e & 1023;
    float4 v = *(const float4*)(x + (size_t)e);
    *(float4*)(out + (size_t)i * 2048 + d) = v;
    ushort4 p;
    p.x = f2bf(v.x); p.y = f2bf(v.y); p.z = f2bf(v.z); p.w = f2bf(v.w);
    *(ushort4*)(xb + (size_t)e) = p;
  } else if (b < 7168) {
    int bb = b - 4096;
    int m  = bb >> 10;
    int tt = bb & 1023;
    const float* in = (m == 0) ? Wq : (m == 1) ? Wk : Wv;
    unsigned short* o = Wcat + (size_t)m * DIM * DIM;
    __shared__ float tile[32][33];
    int bx = (tt & 31) * 32, by = (tt >> 5) * 32;
    int tx = threadIdx.x & 31, ty = threadIdx.x >> 5;
#pragma unroll
    for (int r = 0; r < 32; r += 8)
      tile[ty + r][tx] = in[(size_t)(by + ty + r) * DIM + bx + tx];
    __syncthreads();
#pragma unroll
    for (int r = 0; r < 32; r += 8)
      o[(size_t)(bx + ty + r) * DIM + by + tx] = f2bf(tile[tx][ty + r]);
  } else {
    int i = (b - 7168) * 256 + threadIdx.x;  // 12 blocks -> 3072 elems
    float v = (i < 1024) ? bq[i] : (i < 2048 ? bk[i - 1024] : bv[i - 2048]);
    bcat[i] = v;
  }
}

// ---- transpose V (bf16 [4096][1024]) -> Vt (bf16 [1024][4096]) + zero lrow ----
__global__ __launch_bounds__(256) void transpose_v_kernel(
    const unsigned short* __restrict__ in, int ld_in,
    unsigned short* __restrict__ out, int ld_out,
    float* __restrict__ lrow) {
  if (blockIdx.y == 0 && blockIdx.x < 16)
    lrow[blockIdx.x * 256 + threadIdx.x] = 0.0f;
  __shared__ unsigned short tile[32][33];
  int bx = blockIdx.x * 32;  // c base (V col)
  int by = blockIdx.y * 32;  // r base (V row)
  int tx = threadIdx.x & 31;
  int ty = threadIdx.x >> 5;
#pragma unroll
  for (int r = 0; r < 32; r += 8)
    tile[ty + r][tx] = in[(size_t)(by + ty + r) * ld_in + bx + tx];
  __syncthreads();
#pragma unroll
  for (int r = 0; r < 32; r += 8)
    out[(size_t)(bx + ty + r) * ld_out + by + tx] = tile[tx][ty + r];
}

// ---- QKV GEMM (bf16, BK=64, 8-slot XOR swizzle) + LDS-staged epilogue ----
__global__ __launch_bounds__(256) void gemm_qkv(
    const unsigned short* __restrict__ A, const unsigned short* __restrict__ B,
    const float* __restrict__ bias,
    unsigned char* __restrict__ Qf8, unsigned char* __restrict__ Kf8,
    unsigned short* __restrict__ Vb) {
  const int tid  = threadIdx.x;
  const int wave = tid >> 6;
  const int lane = tid & 63;
  const int wm = wave >> 1, wn = wave & 1;

  int lin = blockIdx.x + 24 * blockIdx.y;
  int xcd = lin & 7, idx = lin >> 3;  // idx in [0,96)
  const int i0 = (xcd * 4 + idx / 24) * 128;
  const int j0 = (idx % 24) * 128;
  const int lda = DIM, ldb = DIM;

  __shared__ unsigned char smem[32768];
  unsigned short* lA = (unsigned short*)smem;              // 16 KB
  unsigned short* lB = (unsigned short*)(smem + 16384);    // 16 KB

  f32x4 acc[4][4];
#pragma unroll
  for (int a = 0; a < 4; ++a)
#pragma unroll
    for (int b = 0; b < 4; ++b) acc[a][b] = (f32x4){0.f, 0.f, 0.f, 0.f};

  const int l15  = lane & 15;
  const int quad = lane >> 4;
  const int r7   = l15 & 7;
  const int cbase = wave * 256;

  for (int kt = 0; kt < DIM; kt += 64) {
    const unsigned short* gA = A + (size_t)i0 * lda + kt;
    const unsigned short* gB = B + (size_t)j0 * ldb + kt;
#pragma unroll
    for (int t = 0; t < 4; ++t) {
      int c  = cbase + t * 64 + lane;
      int r  = c >> 3;
      int sl = c & 7;
      int g  = sl ^ (r & 7);
      __builtin_amdgcn_global_load_lds(
          (const __attribute__((address_space(1))) void*)(gA + (size_t)r * lda + g * 8),
          (__attribute__((address_space(3))) void*)(&lA[c * 8]), 16, 0, 0);
      __builtin_amdgcn_global_load_lds(
          (const __attribute__((address_space(1))) void*)(gB + (size_t)r * ldb + g * 8),
          (__attribute__((address_space(3))) void*)(&lB[c * 8]), 16, 0, 0);
    }
    __syncthreads();
#pragma unroll
    for (int kf = 0; kf < 2; ++kf) {
      bf16x8 af[4], bfr[4];
#pragma unroll
      for (int mt = 0; mt < 4; ++mt)
        af[mt] = *(const bf16x8*)&lA[(wm * 64 + mt * 16 + l15) * 64 + ((kf * 4 + quad) ^ r7) * 8];
#pragma unroll
      for (int nt = 0; nt < 4; ++nt)
        bfr[nt] = *(const bf16x8*)&lB[(wn * 64 + nt * 16 + l15) * 64 + ((kf * 4 + quad) ^ r7) * 8];
#pragma unroll
      for (int mt = 0; mt < 4; ++mt)
#pragma unroll
        for (int nt = 0; nt < 4; ++nt)
          acc[mt][nt] = __builtin_amdgcn_mfma_f32_16x16x32_bf16(af[mt], bfr[nt], acc[mt][nt], 0, 0, 0);
    }
    __syncthreads();
  }

  // ---- LDS-staged epilogue (C/D layout: col=lane&15, row=quad*4+reg) ----
  const int type = j0 >> 10;        // 0=Q, 1=K, 2=V
  const int jl   = j0 & 1023;
  const float scale = (type == 0) ? 0.03125f : 1.0f;

  if (type < 2) {
    unsigned char* ep = smem;
#pragma unroll
    for (int nt = 0; nt < 4; ++nt) {
      int cl = wn * 64 + nt * 16 + l15;
      float bv = bias[j0 + cl];
      int ch = wn * 4 + nt;
#pragma unroll
      for (int mt = 0; mt < 4; ++mt) {
        int rl0 = wm * 64 + mt * 16 + quad * 4;
#pragma unroll
        for (int r = 0; r < 4; ++r) {
          int rl = rl0 + r;
          ep[rl * 128 + (ch ^ (rl & 7)) * 16 + l15] = f2fp8((acc[mt][nt][r] + bv) * scale);
        }
      }
    }
    __syncthreads();
    int row = tid >> 1, half = tid & 1;
    unsigned char* dst = (type == 0 ? Qf8 : Kf8) + (size_t)(i0 + row) * 1024 + jl + half * 64;
#pragma unroll
    for (int k = 0; k < 4; ++k) {
      int sl = (half * 4 + k) ^ (row & 7);
      *(float4*)(dst + k * 16) = *(const float4*)(ep + row * 128 + sl * 16);
    }
  } else {
    unsigned short* ep = (unsigned short*)smem;
#pragma unroll
    for (int nt = 0; nt < 4; ++nt) {
      int cl = wn * 64 + nt * 16 + l15;
      float bv = bias[j0 + cl];
      int chv = cl >> 3, within = cl & 7;
#pragma unroll
      for (int mt = 0; mt < 4; ++mt) {
        int rl0 = wm * 64 + mt * 16 + quad * 4;
#pragma unroll
        for (int r = 0; r < 4; ++r) {
          int rl = rl0 + r;
          ep[rl * 128 + (chv ^ (rl & 7)) * 8 + within] = f2bf(acc[mt][nt][r] + bv);
        }
      }
    }
    __syncthreads();
    int row = tid >> 1, half = tid & 1;
    unsigned short* dst = Vb + (size_t)(i0 + row) * 1024 + jl + half * 64;
#pragma unroll
    for (int k = 0; k < 8; ++k) {
      int sl = (half * 8 + k) ^ (row & 7);
      *(float4*)(dst + k * 8) = *(const float4*)(ep + row * 128 + sl * 8);
    }
  }
}

// ---- scores: fp8 BT GEMM, BK=128, 528 upper-tri tiles (66/XCD) ----
__global__ __launch_bounds__(256) void gemm_sc(
    const unsigned char* __restrict__ A, const unsigned char* __restrict__ B,
    unsigned short* __restrict__ Pr, float* __restrict__ lrow) {
  const int tid  = threadIdx.x;
  const int wave = tid >> 6;
  const int lane = tid & 63;
  const int wm = wave >> 1, wn = wave & 1;

  int b = blockIdx.x;
  int t = (b & 7) * 66 + (b >> 3);
  int bi = (int)floorf((65.0f - sqrtf(4225.0f - 8.0f * (float)t)) * 0.5f);
  while (bi > 0 && (bi * (65 - bi)) / 2 > t) --bi;
  while (((bi + 1) * (64 - bi)) / 2 <= t) ++bi;
  int bj = bi + (t - (bi * (65 - bi)) / 2);
  const int i0 = bi * 128, j0 = bj * 128;
  const int lda = DIM, ldb = DIM;

  __shared__ unsigned char smem[32768];
  unsigned char* lA = smem;            // 16 KB [128][128B]
  unsigned char* lB = smem + 16384;    // 16 KB

  f32x4 acc[4][4];
#pragma unroll
  for (int a = 0; a < 4; ++a)
#pragma unroll
    for (int bb = 0; bb < 4; ++bb) acc[a][bb] = (f32x4){0.f, 0.f, 0.f, 0.f};

  const int l15  = lane & 15;
  const int quad = lane >> 4;
  const int r7   = l15 & 7;
  const int cbase = wave * 256;

  for (int kt = 0; kt < DIM; kt += 128) {
    const unsigned char* gA = A + (size_t)i0 * lda + kt;
    const unsigned char* gB = B + (size_t)j0 * ldb + kt;
#pragma unroll
    for (int tt = 0; tt < 4; ++tt) {
      int c  = cbase + tt * 64 + lane;
      int r  = c >> 3;
      int sl = c & 7;
      int g  = sl ^ (r & 7);
      __builtin_amdgcn_global_load_lds(
          (const __attribute__((address_space(1))) void*)(gA + (size_t)r * lda + g * 16),
          (__attribute__((address_space(3))) void*)(&lA[c * 16]), 16, 0, 0);
      __builtin_amdgcn_global_load_lds(
          (const __attribute__((address_space(1))) void*)(gB + (size_t)r * ldb + g * 16),
          (__attribute__((address_space(3))) void*)(&lB[c * 16]), 16, 0, 0);
    }
    __syncthreads();
#pragma unroll
    for (int kf = 0; kf < 4; ++kf) {
      long av[4], bvv[4];
#pragma unroll
      for (int mt = 0; mt < 4; ++mt) {
        int row = wm * 64 + mt * 16 + l15;
        int ch  = (kf * 2 + (quad >> 1)) ^ r7;
        av[mt] = *(const long*)&lA[row * 128 + ch * 16 + (quad & 1) * 8];
      }
#pragma unroll
      for (int nt = 0; nt < 4; ++nt) {
        int row = wn * 64 + nt * 16 + l15;
        int ch  = (kf * 2 + (quad >> 1)) ^ r7;
        bvv[nt] = *(const long*)&lB[row * 128 + ch * 16 + (quad & 1) * 8];
      }
#pragma unroll
      for (int mt = 0; mt < 4; ++mt)
#pragma unroll
        for (int nt = 0; nt < 4; ++nt)
          acc[mt][nt] = __builtin_amdgcn_mfma_f32_16x16x32_fp8_fp8(av[mt], bvv[nt], acc[mt][nt], 0, 0, 0);
    }
    __syncthreads();
  }

  // ---- epilogue: bf16 P tile via LDS + lrow sums ----
  unsigned short* ep = (unsigned short*)smem;
  float lsum[4][4];
#pragma unroll
  for (int mt = 0; mt < 4; ++mt)
#pragma unroll
    for (int r = 0; r < 4; ++r) lsum[mt][r] = 0.0f;
#pragma unroll
  for (int nt = 0; nt < 4; ++nt) {
    int cl = wn * 64 + nt * 16 + l15;
    int gc = j0 + cl;
    int chv = cl >> 3, within = cl & 7;
#pragma unroll
    for (int mt = 0; mt < 4; ++mt) {
      int rl0 = wm * 64 + mt * 16 + quad * 4;
#pragma unroll
      for (int r = 0; r < 4; ++r) {
        int rl = rl0 + r;
        int row = i0 + rl;
        float e = (gc >= row) ? __expf(acc[mt][nt][r] - 4.0f) : 0.0f;
        unsigned short eb = f2bf(e);
        ep[rl * 128 + (chv ^ (rl & 7)) * 8 + within] = eb;
        lsum[mt][r] += bf2f(eb);  // sum what PV will actually read
      }
    }
  }
#pragma unroll
  for (int mt = 0; mt < 4; ++mt)
#pragma unroll
    for (int r = 0; r < 4; ++r) {
      float s = lsum[mt][r];
      s += __shfl_xor(s, 1);
      s += __shfl_xor(s, 2);
      s += __shfl_xor(s, 4);
      s += __shfl_xor(s, 8);
      if (l15 == 0)
        unsafeAtomicAdd(&lrow[i0 + wm * 64 + mt * 16 + quad * 4 + r], s);
    }
  __syncthreads();
  int row = tid >> 1, half = tid & 1;
  unsigned short* dst = Pr + (size_t)(i0 + row) * SEQ + j0 + half * 64;
#pragma unroll
  for (int k = 0; k < 8; ++k) {
    int sl = (half * 8 + k) ^ (row & 7);
    *(float4*)(dst + k * 8) = *(const float4*)(ep + row * 128 + sl * 8);
  }
}

// ---- PV: bf16 BT GEMM, BK=64, BALANCED split-K z=4, NO atomics ----
// Per row-block: K-range [i0,4096) split into 4 equal 64-aligned chunks.
// All 1024 blocks live; partial sums stored as bf16 via coalesced LDS
// epilogue into Ppart[z][4096][1024]. Reduced by reduce_kernel.
__global__ __launch_bounds__(256) void gemm_pv(
    const unsigned short* __restrict__ A, int lda,
    const unsigned short* __restrict__ B, int ldb,
    unsigned short* __restrict__ Ppart) {
  const int tid  = threadIdx.x;
  const int wave = tid >> 6;
  const int lane = tid & 63;
  const int wm = wave >> 1, wn = wave & 1;

  const int i0 = blockIdx.y * 128, j0 = blockIdx.x * 128;
  const int bz = blockIdx.z;
  const int n_it = (SEQ - i0) >> 6;                 // total 64-wide iters for this row
  const int kstart = i0 + ((n_it * bz) >> 2) * 64;
  const int kend   = i0 + ((n_it * (bz + 1)) >> 2) * 64;

  __shared__ unsigned char smem[32768];
  unsigned short* lA = (unsigned short*)smem;           // 16 KB
  unsigned short* lB = (unsigned short*)(smem + 16384); // 16 KB

  f32x4 acc[4][4];
#pragma unroll
  for (int a = 0; a < 4; ++a)
#pragma unroll
    for (int b = 0; b < 4; ++b) acc[a][b] = (f32x4){0.f, 0.f, 0.f, 0.f};

  const int l15  = lane & 15;
  const int quad = lane >> 4;
  const int r7   = l15 & 7;
  const int cbase = wave * 256;

  for (int kt = kstart; kt < kend; kt += 64) {
    const unsigned short* gA = A + (size_t)i0 * lda + kt;
    const unsigned short* gB = B + (size_t)j0 * ldb + kt;
#pragma unroll
    for (int t = 0; t < 4; ++t) {
      int c  = cbase + t * 64 + lane;
      int r  = c >> 3;
      int sl = c & 7;
      int g  = sl ^ (r & 7);
      __builtin_amdgcn_global_load_lds(
          (const __attribute__((address_space(1))) void*)(gA + (size_t)r * lda + g * 8),
          (__attribute__((address_space(3))) void*)(&lA[c * 8]), 16, 0, 0);
      __builtin_amdgcn_global_load_lds(
          (const __attribute__((address_space(1))) void*)(gB + (size_t)r * ldb + g * 8),
          (__attribute__((address_space(3))) void*)(&lB[c * 8]), 16, 0, 0);
    }
    __syncthreads();
#pragma unroll
    for (int kf = 0; kf < 2; ++kf) {
      bf16x8 af[4], bfr[4];
#pragma unroll
      for (int mt = 0; mt < 4; ++mt)
        af[mt] = *(const bf16x8*)&lA[(wm * 64 + mt * 16 + l15) * 64 + ((kf * 4 + quad) ^ r7) * 8];
#pragma unroll
      for (int nt = 0; nt < 4; ++nt)
        bfr[nt] = *(const bf16x8*)&lB[(wn * 64 + nt * 16 + l15) * 64 + ((kf * 4 + quad) ^ r7) * 8];
#pragma unroll
      for (int mt = 0; mt < 4; ++mt)
#pragma unroll
        for (int nt = 0; nt < 4; ++nt)
          acc[mt][nt] = __builtin_amdgcn_mfma_f32_16x16x32_bf16(af[mt], bfr[nt], acc[mt][nt], 0, 0, 0);
    }
    __syncthreads();
  }

  // ---- LDS-staged epilogue: bf16 partial tile, coalesced plain stores ----
  unsigned short* ep = (unsigned short*)smem;
#pragma unroll
  for (int nt = 0; nt < 4; ++nt) {
    int cl = wn * 64 + nt * 16 + l15;
    int chv = cl >> 3, within = cl & 7;
#pragma unroll
    for (int mt = 0; mt < 4; ++mt) {
      int rl0 = wm * 64 + mt * 16 + quad * 4;
#pragma unroll
      for (int r = 0; r < 4; ++r) {
        int rl = rl0 + r;
        ep[rl * 128 + (chv ^ (rl & 7)) * 8 + within] = f2bf(acc[mt][nt][r]);
      }
    }
  }
  __syncthreads();
  int row = tid >> 1, half = tid & 1;
  unsigned short* dst = Ppart + (size_t)bz * SEQ * 1024 +
                        (size_t)(i0 + row) * 1024 + j0 + half * 64;
#pragma unroll
  for (int k = 0; k < 8; ++k) {
    int sl = (half * 8 + k) ^ (row & 7);
    *(float4*)(dst + k * 8) = *(const float4*)(ep + row * 128 + sl * 8);
  }
}

// ---- reduce: out[:,1024:2048] = (sum_z Ppart[z]) / lrow ----
__global__ __launch_bounds__(256) void reduce_kernel(
    const unsigned short* __restrict__ Ppart, const float* __restrict__ lrow,
    float* __restrict__ out) {
  int idx = blockIdx.x * 256 + threadIdx.x;  // 524288 threads
  int row = idx >> 7;
  int c0  = (idx & 127) << 3;
  float inv = 1.0f / lrow[row];
  float s[8];
#pragma unroll
  for (int e = 0; e < 8; ++e) s[e] = 0.0f;
  const size_t base = (size_t)row * 1024 + c0;
#pragma unroll
  for (int z = 0; z < 4; ++z) {
    ushort4 a = *(const ushort4*)(Ppart + (size_t)z * SEQ * 1024 + base);
    ushort4 b = *(const ushort4*)(Ppart + (size_t)z * SEQ * 1024 + base + 4);
    s[0] += bf2f(a.x); s[1] += bf2f(a.y); s[2] += bf2f(a.z); s[3] += bf2f(a.w);
    s[4] += bf2f(b.x); s[5] += bf2f(b.y); s[6] += bf2f(b.z); s[7] += bf2f(b.w);
  }
  float* d = out + (size_t)row * 2048 + 1024 + c0;
  *(float4*)(d)     = make_float4(s[0] * inv, s[1] * inv, s[2] * inv, s[3] * inv);
  *(float4*)(d + 4) = make_float4(s[4] * inv, s[5] * inv, s[6] * inv, s[7] * inv);
}

extern "C" void kernel_launch(void* const* d_in, const int* in_sizes, int n_in,
                              void* d_out, int out_size, void* d_ws, size_t ws_size,
                              hipStream_t stream) {
  const float* x  = (const float*)d_in[0];
  const float* Wk = (const float*)d_in[1];
  const float* bk = (const float*)d_in[2];
  const float* Wq = (const float*)d_in[3];
  const float* bq = (const float*)d_in[4];
  const float* Wv = (const float*)d_in[5];
  const float* bv = (const float*)d_in[6];
  float* out = (float*)d_out;

  char* ws = (char*)d_ws;
  unsigned short* Xb    = (unsigned short*)(ws);                  // 8 MB  [4096][1024] bf16
  unsigned short* Wcat  = (unsigned short*)(ws + (8ull << 20));   // 6 MB  [3072][1024] bf16
  float*          bcat  = (float*)(ws + (14ull << 20));           // 12 KB
  unsigned char*  Qf8   = (unsigned char*)(ws + (15ull << 20));   // 4 MB  [4096][1024] fp8
  unsigned char*  Kf8   = (unsigned char*)(ws + (19ull << 20));   // 4 MB  [4096][1024] fp8
  unsigned short* Pr    = (unsigned short*)(ws + (23ull << 20));  // 32 MB [4096][4096] bf16
  unsigned short* Vb    = (unsigned short*)(ws + (55ull << 20));  // 8 MB  [4096][1024] bf16
  unsigned short* Vt    = (unsigned short*)(ws + (63ull << 20));  // 8 MB  [1024][4096] bf16
  float*          lrow  = (float*)(ws + (71ull << 20));           // 16 KB
  unsigned short* Ppart = (unsigned short*)(ws + (72ull << 20));  // 32 MB [4][4096][1024] bf16

  // 1. x -> bf16 + out[:, :1024] = x ; W transposes ; bias concat
  setup_kernel<<<7180, 256, 0, stream>>>(x, Xb, out, Wq, Wk, Wv, bq, bk, bv, Wcat, bcat);

  // 2. fused QKV GEMM (bf16) -> Qf8 (x1/32), Kf8, Vb
  gemm_qkv<<<dim3(24, 32), 256, 0, stream>>>(Xb, Wcat, bcat, Qf8, Kf8, Vb);

  // 3. Vt = V^T (bf16); also zeroes lrow
  transpose_v_kernel<<<dim3(DIM / 32, SEQ / 32), 256, 0, stream>>>(
      Vb, DIM, Vt, SEQ, lrow);

  // 4. scores upper-tri tiles (fp8 inputs) -> bf16 Pr + lrow sums
  gemm_sc<<<528, 256, 0, stream>>>(Qf8, Kf8, Pr, lrow);

  // 5. PV partials: balanced split-K x4, plain bf16 stores (no atomics)
  gemm_pv<<<dim3(8, 32, 4), 256, 0, stream>>>(Pr, SEQ, Vt, SEQ, Ppart);

  // 6. out[:,1024:2048] = (sum partials) / lrow
  reduce_kernel<<<2048, 256, 0, stream>>>(Ppart, lrow, out);
}